// Round 2
// baseline (232.021 us; speedup 1.0000x reference)
//
#include <hip/hip_runtime.h>

// B=64, N=2048, DIM_IN=DIM_OUT=64, CHEB_K=3, EMBED_DIM=10
#define NN 2048
#define BB 64
#define CC 64
#define ED 10
#define KK 3
#define JJ (BB * CC)   // 4096

typedef unsigned short ushort_t;
typedef __attribute__((ext_vector_type(8))) short short8;   // 8 bf16 = 4 VGPRs
typedef __attribute__((ext_vector_type(4))) float f32x4;

typedef const __attribute__((address_space(1))) unsigned* gptr_t;
typedef __attribute__((address_space(3))) unsigned* lptr_t;

static __device__ __forceinline__ ushort_t f2bf(float f) {
    union { float f; unsigned u; } x{f};
    unsigned r = x.u + 0x7FFF + ((x.u >> 16) & 1);  // RTN-even
    return (ushort_t)(r >> 16);
}
static __device__ __forceinline__ float bf2f(ushort_t h) {
    union { unsigned u; float f; } x;
    x.u = ((unsigned)h) << 16;
    return x.f;
}

// ---------------------------------------------------------------------------
// Kernel 1 (merged prep): blockIdx selects role.
//   [0, NN)            : supports — A_bf16[n][m] = softmax(relu(E E^T)) row n
//   [NN, 2*NN)         : transpose — x[b][n][c] -> xT[(b*64+c)][n], xN[n][j]
//   [2*NN, 2*NN+30)    : wprep — Wp[d][k][i][o] fp32 -> WpT[(d*3+k)][o][i] bf16
// ---------------------------------------------------------------------------
__global__ __launch_bounds__(256) void prep_kernel(const float* __restrict__ E,
                                                   const float* __restrict__ x,
                                                   const float* __restrict__ Wp,
                                                   ushort_t* __restrict__ Ab,
                                                   ushort_t* __restrict__ xT,
                                                   ushort_t* __restrict__ xN,
                                                   ushort_t* __restrict__ WpT) {
    const int bid = blockIdx.x;
    const int tid = threadIdx.x;

    __shared__ float tb[64][68];
    __shared__ float red[8];

    if (bid < NN) {
        // ---- supports row n = bid ----
        const int n = bid;
        float en[ED];
#pragma unroll
        for (int d = 0; d < ED; ++d) en[d] = E[n * ED + d];

        float sv[NN / 256];
        float lmax = 0.0f;  // relu >= 0
#pragma unroll
        for (int j = 0; j < NN / 256; ++j) {
            const int m = tid + j * 256;
            const float* Em = E + m * ED;
            float dot = 0.0f;
#pragma unroll
            for (int d = 0; d < ED; ++d) dot += en[d] * Em[d];
            float s = fmaxf(dot, 0.0f);
            sv[j] = s;
            lmax = fmaxf(lmax, s);
        }
#pragma unroll
        for (int off = 32; off > 0; off >>= 1) lmax = fmaxf(lmax, __shfl_down(lmax, off, 64));
        if ((tid & 63) == 0) red[tid >> 6] = lmax;
        __syncthreads();
        const float bmax = fmaxf(fmaxf(red[0], red[1]), fmaxf(red[2], red[3]));

        float lsum = 0.0f;
#pragma unroll
        for (int j = 0; j < NN / 256; ++j) {
            sv[j] = __expf(sv[j] - bmax);
            lsum += sv[j];
        }
#pragma unroll
        for (int off = 32; off > 0; off >>= 1) lsum += __shfl_down(lsum, off, 64);
        if ((tid & 63) == 0) red[4 + (tid >> 6)] = lsum;
        __syncthreads();
        const float inv = 1.0f / (red[4] + red[5] + red[6] + red[7]);

#pragma unroll
        for (int j = 0; j < NN / 256; ++j) {
            Ab[(size_t)n * NN + tid + j * 256] = f2bf(sv[j] * inv);
        }
    } else if (bid < 2 * NN) {
        // ---- transpose tile ----
        const int t = bid - NN;
        const int n0 = (t & 31) * 64;
        const int b = t >> 5;

#pragma unroll
        for (int l = 0; l < 4; ++l) {
            const int idx = tid + l * 256;
            const int nn = idx >> 4;
            const int c4 = (idx & 15) << 2;
            const float4 v = *(const float4*)(x + ((size_t)b * NN + n0 + nn) * CC + c4);
            tb[c4 + 0][nn] = v.x;
            tb[c4 + 1][nn] = v.y;
            tb[c4 + 2][nn] = v.z;
            tb[c4 + 3][nn] = v.w;
        }
        __syncthreads();

#pragma unroll
        for (int l = 0; l < 2; ++l) {
            const int idx = tid + l * 256;
            const int c = idx >> 3;
            const int ch = (idx & 7) << 3;
            ushort_t pack[8];
#pragma unroll
            for (int e = 0; e < 8; ++e) pack[e] = f2bf(tb[c][ch + e]);
            *(float4*)(xT + (size_t)(b * 64 + c) * NN + n0 + ch) = *(float4*)pack;
        }
#pragma unroll
        for (int l = 0; l < 2; ++l) {
            const int idx = tid + l * 256;
            const int nn = idx >> 3;
            const int cg = (idx & 7) << 3;
            ushort_t pack[8];
#pragma unroll
            for (int e = 0; e < 8; ++e) pack[e] = f2bf(tb[cg + e][nn]);
            *(float4*)(xN + (size_t)(n0 + nn) * JJ + b * 64 + cg) = *(float4*)pack;
        }
    } else {
        // ---- wprep slice dk = bid - 2*NN ----
        const int dk = bid - 2 * NN;
        const float* src = Wp + (size_t)dk * CC * CC;

#pragma unroll
        for (int l = 0; l < 4; ++l) {
            const int idx = tid + l * 256;
            const int i = idx >> 4;
            const int o4 = (idx & 15) << 2;
            const float4 v = *(const float4*)(src + i * CC + o4);
            tb[o4 + 0][i] = v.x;
            tb[o4 + 1][i] = v.y;
            tb[o4 + 2][i] = v.z;
            tb[o4 + 3][i] = v.w;
        }
        __syncthreads();

#pragma unroll
        for (int l = 0; l < 2; ++l) {
            const int idx = tid + l * 256;
            const int o = idx >> 3;
            const int ic = (idx & 7) << 3;
            ushort_t pack[8];
#pragma unroll
            for (int e = 0; e < 8; ++e) pack[e] = f2bf(tb[o][ic + e]);
            *(float4*)(WpT + (size_t)dk * CC * CC + o * CC + ic) = *(float4*)pack;
        }
    }
}

// ---------------------------------------------------------------------------
// Kernel 2: tiny bf16 transpose At[m][n] = Ab[n][m] (64x64 tiles, ~17 MB).
// Needed so the A^2 GEMM can run NT (both operands K-major).
// ---------------------------------------------------------------------------
__global__ __launch_bounds__(256) void trans_kernel(const ushort_t* __restrict__ Ab,
                                                    ushort_t* __restrict__ At) {
    const int bx = blockIdx.x;  // source col-tile (At row-tile)
    const int by = blockIdx.y;  // source row-tile
    const int tid = threadIdx.x;
    __shared__ ushort_t tb[64][72];  // 144B stride: 16B-aligned rows

#pragma unroll
    for (int l = 0; l < 2; ++l) {
        const int idx = tid + l * 256;
        const int r = idx >> 3;
        const int c0 = (idx & 7) << 3;
        const float4 v = *(const float4*)(Ab + (size_t)(by * 64 + r) * NN + bx * 64 + c0);
        const ushort_t* p = (const ushort_t*)&v;
#pragma unroll
        for (int e = 0; e < 8; ++e) tb[c0 + e][r] = p[e];
    }
    __syncthreads();
#pragma unroll
    for (int l = 0; l < 2; ++l) {
        const int idx = tid + l * 256;
        const int m = idx >> 3;
        const int c0 = (idx & 7) << 3;
        ushort_t pack[8];
#pragma unroll
        for (int e = 0; e < 8; ++e) pack[e] = tb[m][c0 + e];
        *(float4*)(At + (size_t)(bx * 64 + m) * NN + by * 64 + c0) = *(float4*)pack;
    }
}

// ---------------------------------------------------------------------------
// Kernel 3: T2 = 2*A@A - I  (row-major bf16 out). Proven 128^2 dbuf structure,
// NT with Bt = A^T. 17.2 GF.
// ---------------------------------------------------------------------------
__global__ __launch_bounds__(256) void gemm_t2(const ushort_t* __restrict__ A,
                                               const ushort_t* __restrict__ Bt,
                                               ushort_t* __restrict__ C) {
    const int j0 = blockIdx.x * 128;
    const int m0 = blockIdx.y * 128;
    const int tid = threadIdx.x;
    const int lane = tid & 63;
    const int l16 = lane & 15;
    const int quad = lane >> 4;
    const int w = tid >> 6;
    const int wm = (w >> 1) * 64;
    const int wj = (w & 1) * 64;
    const int lr = lane >> 3;
    const int lc = lane & 7;
    const int swz = lc ^ lr;

    __shared__ ushort_t As[2][128 * 64];
    __shared__ ushort_t Bs[2][128 * 64];

    f32x4 acc[4][4];
#pragma unroll
    for (int mi = 0; mi < 4; ++mi)
#pragma unroll
        for (int ji = 0; ji < 4; ++ji) acc[mi][ji] = (f32x4){0.f, 0.f, 0.f, 0.f};

#pragma unroll
    for (int inst = 0; inst < 4; ++inst) {
        const int rbase = w * 32 + inst * 8;
        const int row = rbase + lr;
        __builtin_amdgcn_global_load_lds(
            (gptr_t)(A + (size_t)(m0 + row) * NN + swz * 8),
            (lptr_t)&As[0][rbase * 64], 16, 0, 0);
        __builtin_amdgcn_global_load_lds(
            (gptr_t)(Bt + (size_t)(j0 + row) * NN + swz * 8),
            (lptr_t)&Bs[0][rbase * 64], 16, 0, 0);
    }

    for (int it = 0; it < NN / 64; ++it) {
        const int cur = it & 1;
        __syncthreads();

        if (it + 1 < NN / 64) {
            const int k0 = (it + 1) * 64;
#pragma unroll
            for (int inst = 0; inst < 4; ++inst) {
                const int rbase = w * 32 + inst * 8;
                const int row = rbase + lr;
                __builtin_amdgcn_global_load_lds(
                    (gptr_t)(A + (size_t)(m0 + row) * NN + k0 + swz * 8),
                    (lptr_t)&As[1 - cur][rbase * 64], 16, 0, 0);
                __builtin_amdgcn_global_load_lds(
                    (gptr_t)(Bt + (size_t)(j0 + row) * NN + k0 + swz * 8),
                    (lptr_t)&Bs[1 - cur][rbase * 64], 16, 0, 0);
            }
        }

#pragma unroll
        for (int ks = 0; ks < 64; ks += 32) {
            const int qb = (ks >> 3) + quad;
            short8 av[4], bv[4];
#pragma unroll
            for (int mi = 0; mi < 4; ++mi) {
                const int rA = wm + mi * 16 + l16;
                av[mi] = *(const short8*)&As[cur][rA * 64 + ((qb ^ (rA & 7)) << 3)];
            }
#pragma unroll
            for (int ji = 0; ji < 4; ++ji) {
                const int rB = wj + ji * 16 + l16;
                bv[ji] = *(const short8*)&Bs[cur][rB * 64 + ((qb ^ (rB & 7)) << 3)];
            }
#pragma unroll
            for (int mi = 0; mi < 4; ++mi)
#pragma unroll
                for (int ji = 0; ji < 4; ++ji)
                    acc[mi][ji] = __builtin_amdgcn_mfma_f32_16x16x32_bf16(
                        av[mi], bv[ji], acc[mi][ji], 0, 0, 0);
        }
    }

    // C/D layout (16x16x32): col j = lane&15, row m = quad*4 + reg.
#pragma unroll
    for (int mi = 0; mi < 4; ++mi) {
#pragma unroll
        for (int ji = 0; ji < 4; ++ji) {
            const int j = j0 + wj + ji * 16 + l16;
            const int mb = m0 + wm + mi * 16 + quad * 4;
#pragma unroll
            for (int r = 0; r < 4; ++r) {
                const float v = 2.0f * acc[mi][ji][r] - ((mb + r) == j ? 1.0f : 0.0f);
                C[(size_t)(mb + r) * NN + j] = f2bf(v);
            }
        }
    }
}

// ---------------------------------------------------------------------------
// Kernel 4: 256^2 / BK=64 / 8-wave / 8-phase counted-vmcnt GEMM. One dispatch
// computes BOTH y1 = A@x (rows < 2048) and y2 = T2@x (rows >= 2048):
// M=4096, N=4096, K=2048 -> grid 256 = 1 block/CU.
//
// RACE-FIXED stage schedule (S2): with a 2-tile double buffer, a half-tile of
// tile t+2 may be staged only AFTER the last ds_read of tile t from that LDS
// region is barrier-fenced. Read completion: B halves done at the tile's 2nd
// phase, A halves at its 3rd. Earliest-safe schedule:
//   phi1: stage t_b h2 | phi2: t_b h3 | phi3: t_a+2 h2 | phi4: t_a+2 h3,h0
//   phi5: t_a+2 h1    | phi8: t_b+2 h0,h1
// Drains: phi4 vmcnt(6) -> t_b landed (6 = t_a+2 h2,h3,h0 in flight);
//         phi8 vmcnt(4) -> t_a+2 landed (4 = t_b+2 h0,h1 in flight).
// Every stage lands >= 2 phases before its drain point.
// ---------------------------------------------------------------------------
#define STAGE_HALF(buf, h3, kt) do {                                                        \
    const ushort_t* s_ = ((h3) < 2) ? srcA : srcB;                                          \
    __builtin_amdgcn_global_load_lds(                                                       \
        (gptr_t)(s_ + (size_t)(((h3) & 1) * 2) * 64 * NN + (size_t)(kt) * 64),              \
        (lptr_t)&lds[buf][(h3) >= 2][(((h3) & 1) * 2) * 4096 + dstoff], 16, 0, 0);          \
    __builtin_amdgcn_global_load_lds(                                                       \
        (gptr_t)(s_ + (size_t)(((h3) & 1) * 2 + 1) * 64 * NN + (size_t)(kt) * 64),          \
        (lptr_t)&lds[buf][(h3) >= 2][(((h3) & 1) * 2 + 1) * 4096 + dstoff], 16, 0, 0);      \
} while (0)

#define LDA_Q(buf, qm) do {                                                                 \
    _Pragma("unroll") for (int mi_ = 0; mi_ < 4; ++mi_)                                     \
    _Pragma("unroll") for (int ks_ = 0; ks_ < 2; ++ks_)                                     \
        a[mi_][ks_] = *(const short8*)&lds[buf][0][((aRG + (qm) * 4 + mi_) * 2 + ks_) * 512 + rdofs]; \
} while (0)

#define LDB_Q(buf, qn) do {                                                                 \
    _Pragma("unroll") for (int ni_ = 0; ni_ < 2; ++ni_)                                     \
    _Pragma("unroll") for (int ks_ = 0; ks_ < 2; ++ks_)                                     \
        b[(qn) * 2 + ni_][ks_] = *(const short8*)&lds[buf][1][((bRG + (qn) * 2 + ni_) * 2 + ks_) * 512 + rdofs]; \
} while (0)

#define MFMA_Q(qm, qn) do {                                                                 \
    __builtin_amdgcn_s_setprio(1);                                                          \
    _Pragma("unroll") for (int mi_ = 0; mi_ < 4; ++mi_)                                     \
    _Pragma("unroll") for (int nn_ = 0; nn_ < 2; ++nn_) {                                   \
        acc[(qm) * 4 + mi_][(qn) * 2 + nn_] = __builtin_amdgcn_mfma_f32_16x16x32_bf16(      \
            a[mi_][0], b[(qn) * 2 + nn_][0], acc[(qm) * 4 + mi_][(qn) * 2 + nn_], 0, 0, 0); \
        acc[(qm) * 4 + mi_][(qn) * 2 + nn_] = __builtin_amdgcn_mfma_f32_16x16x32_bf16(      \
            a[mi_][1], b[(qn) * 2 + nn_][1], acc[(qm) * 4 + mi_][(qn) * 2 + nn_], 0, 0, 0); \
    }                                                                                       \
    __builtin_amdgcn_s_setprio(0);                                                          \
} while (0)

#define PH_SYNC do {                                                                        \
    __builtin_amdgcn_s_barrier();                                                           \
    asm volatile("s_waitcnt lgkmcnt(0)" ::: "memory");                                      \
    __builtin_amdgcn_sched_barrier(0);                                                      \
} while (0)

#define PH_END do {                                                                         \
    __builtin_amdgcn_sched_barrier(0);                                                      \
    __builtin_amdgcn_s_barrier();                                                           \
} while (0)

__global__ __launch_bounds__(512, 2) void gemm8(const ushort_t* __restrict__ Ab,
                                                const ushort_t* __restrict__ T2b,
                                                const ushort_t* __restrict__ Bt,
                                                ushort_t* __restrict__ y1N,
                                                ushort_t* __restrict__ y2N) {
    // bijective XCD swizzle (gridDim.x = 256, 256 % 8 == 0)
    int bid = blockIdx.x;
    bid = (bid & 7) * 32 + (bid >> 3);
    const int bx = bid & 15;        // j-tile
    const int by = bid >> 4;        // m-tile (0..7 -> y1, 8..15 -> y2)
    const int j0 = bx * 256;
    const int m0 = by * 256;

    const ushort_t* Arows = (by < 8) ? (Ab + (size_t)m0 * NN) : (T2b + (size_t)(m0 - NN) * NN);
    const ushort_t* Brows = Bt + (size_t)j0 * NN;
    ushort_t* Crow = (by < 8) ? (y1N + (size_t)m0 * JJ) : (y2N + (size_t)(m0 - NN) * JJ);

    const int tid = threadIdx.x;
    const int w = tid >> 6;
    const int lane = tid & 63;
    const int l16 = lane & 15;
    const int quad = lane >> 4;
    const int wm = (w >> 2) * 128;  // wave output: rows [wm,wm+128) x cols [wn,wn+64)
    const int wn = (w & 3) * 64;
    const int aRG = (w >> 2) * 8;   // A 16-row subtile group base
    const int bRG = (w & 3) * 4;    // B 16-row subtile group base
    // swizzled ds_read offset (ushorts): row l16, k-chunk quad, st_16x32 XOR
    const int rdofs = l16 * 32 + ((quad * 8) ^ ((l16 & 8) * 2));

    // staging: linear LDS dest (base + lane*16B); inverse-swizzle the SOURCE
    const int r16s = lane >> 2;                       // dest row within subtile
    const int cx = (lane & 3) ^ ((r16s >> 3) << 1);   // inverse st_16x32 on k-chunk
    const int rowbase = (w >> 1) * 16 + r16s;         // row within 64-row group
    const int kofs = (w & 1) * 32 + cx * 8;           // k element offset in K-tile
    const ushort_t* srcA = Arows + (size_t)rowbase * NN + kofs;
    const ushort_t* srcB = Brows + (size_t)rowbase * NN + kofs;
    const int dstoff = tid * 8;                       // ushorts within 8KB unit

    __shared__ ushort_t lds[2][2][16384];  // [dbuf][A/B][32 KB tile] = 128 KB

    f32x4 acc[8][4];
#pragma unroll
    for (int mi = 0; mi < 8; ++mi)
#pragma unroll
        for (int ni = 0; ni < 4; ++ni) acc[mi][ni] = (f32x4){0.f, 0.f, 0.f, 0.f};

    short8 a[4][2], b[4][2];

    // Prologue: tile0 all 4 halves + tile1 h0,h1 (A); vmcnt(4) -> tile0 landed.
    STAGE_HALF(0, 0, 0); STAGE_HALF(0, 1, 0); STAGE_HALF(0, 2, 0); STAGE_HALF(0, 3, 0);
    STAGE_HALF(1, 0, 1); STAGE_HALF(1, 1, 1);
    asm volatile("s_waitcnt vmcnt(4)" ::: "memory");
    __builtin_amdgcn_s_barrier();

    // 16 iterations x 2 K-tiles (K = 2048 = 32 x BK64). buf0 = even tiles,
    // buf1 = odd tiles.
#pragma unroll 1
    for (int i = 0; i < 16; ++i) {
        const int tb_ = 2 * i + 1;
        const int ta2 = 2 * i + 2;
        const int tb2 = 2 * i + 3;
        const bool stg = (i < 15);

        // phi1: tile 2i (buf0), quadrant (qm0,qn0); stage t_b h2 (buf1 B-lo:
        // old buf1 B reads finished 2 phases ago)
        LDA_Q(0, 0); LDB_Q(0, 0);
        STAGE_HALF(1, 2, tb_);
        PH_SYNC; MFMA_Q(0, 0); PH_END;
        // phi2: (qm0,qn1); stage t_b h3
        LDB_Q(0, 1);
        STAGE_HALF(1, 3, tb_);
        PH_SYNC; MFMA_Q(0, 1); PH_END;
        // phi3: (qm1,qn1); stage t_a+2 h2 (buf0 B-lo: buf0 B reads done phi2)
        LDA_Q(0, 1);
        if (stg) STAGE_HALF(0, 2, ta2);
        PH_SYNC; MFMA_Q(1, 1); PH_END;
        // phi4: (qm1,qn0) — regs live; stage t_a+2 h3,h0 (buf0 A reads done
        // phi3, fenced by phi3's closing barrier); drain t_b
        if (stg) { STAGE_HALF(0, 3, ta2); STAGE_HALF(0, 0, ta2); }
        __builtin_amdgcn_s_barrier();
        MFMA_Q(1, 0);
        __builtin_amdgcn_sched_barrier(0);
        if (stg) { asm volatile("s_waitcnt vmcnt(6)" ::: "memory"); }
        else     { asm volatile("s_waitcnt vmcnt(0)" ::: "memory"); }
        __builtin_amdgcn_s_barrier();

        // phi5: tile 2i+1 (buf1), (qm0,qn0); stage t_a+2 h1
        LDA_Q(1, 0); LDB_Q(1, 0);
        if (stg) STAGE_HALF(0, 1, ta2);
        PH_SYNC; MFMA_Q(0, 0); PH_END;
        // phi6: (qm0,qn1)
        LDB_Q(1, 1);
        PH_SYNC; MFMA_Q(0, 1); PH_END;
        // phi7: (qm1,qn1)
        LDA_Q(1, 1);
        PH_SYNC; MFMA_Q(1, 1); PH_END;
        // phi8: (qm1,qn0); stage t_b+2 h0,h1 (buf1 A reads done phi7, fenced);
        // drain t_a+2
        if (stg) { STAGE_HALF(1, 0, tb2); STAGE_HALF(1, 1, tb2); }
        __builtin_amdgcn_s_barrier();
        MFMA_Q(1, 0);
        __builtin_amdgcn_sched_barrier(0);
        if (stg) { asm volatile("s_waitcnt vmcnt(4)" ::: "memory"); }
        __builtin_amdgcn_s_barrier();
    }

    // Epilogue: C/D col = l16, row = quad*4 + r. Row-major bf16 out.
#pragma unroll
    for (int mi = 0; mi < 8; ++mi) {
#pragma unroll
        for (int ni = 0; ni < 4; ++ni) {
            const int j = j0 + wn + ni * 16 + l16;
            const int mb = wm + mi * 16 + quad * 4;
#pragma unroll
            for (int r = 0; r < 4; ++r)
                Crow[(size_t)(mb + r) * JJ + j] = f2bf(acc[mi][ni][r]);
        }
    }
}

#undef STAGE_HALF
#undef LDA_Q
#undef LDB_Q
#undef MFMA_Q
#undef PH_SYNC
#undef PH_END

// ---------------------------------------------------------------------------
// Kernel 5: MFMA epilogue (unchanged from the verified round-4 version).
// One block per node n: [B=64 x KI=192] @ [KI=192 x O=64] via 24 MFMAs/wave.
// ---------------------------------------------------------------------------
#define XLD 200  // LDS row stride (bf16): 400 B -> 2-way bank alias (free)
__global__ __launch_bounds__(256) void out_kernel(const float* __restrict__ E,
                                                  const ushort_t* __restrict__ WpT,
                                                  const float* __restrict__ bp,
                                                  const ushort_t* __restrict__ xN,
                                                  const ushort_t* __restrict__ y1N,
                                                  const ushort_t* __restrict__ y2N,
                                                  float* __restrict__ out) {
    const int n = blockIdx.x;
    const int tid = threadIdx.x;

    __shared__ ushort_t xg[BB * XLD];  // 25.6 KB: xg[b][k*64+i]
    __shared__ ushort_t Wt[CC * XLD];  // 25.6 KB: Wt[o][k*64+i]
    __shared__ float en_s[ED];
    __shared__ float bias_s[CC];

    if (tid < ED) en_s[tid] = E[n * ED + tid];
    __syncthreads();

    float en[ED];
#pragma unroll
    for (int d = 0; d < ED; ++d) en[d] = en_s[d];

    if (tid < CC) {
        float bsum = 0.0f;
#pragma unroll
        for (int d = 0; d < ED; ++d) bsum += en[d] * bp[d * CC + tid];
        bias_s[tid] = bsum;
    }

    // stage X rows: 3 sources x 512 chunks of 8 bf16 (contiguous 8 KB each)
#pragma unroll
    for (int k = 0; k < KK; ++k) {
        const ushort_t* src = (k == 0) ? xN : (k == 1) ? y1N : y2N;
        const float4* srow = (const float4*)(src + (size_t)n * JJ);
        for (int idx = tid; idx < JJ / 8; idx += 256) {
            *(float4*)&xg[(idx >> 3) * XLD + k * 64 + ((idx & 7) << 3)] = srow[idx];
        }
    }

    // synthesize Wt[o][ki] bf16: 1536 chunks of 8, fp32 accumulate over d
    for (int t = tid; t < CC * 24; t += 256) {
        const int o = t / 24;
        const int kc = t % 24;
        const int k = kc >> 3;
        const int ic = (kc & 7) << 3;
        float s[8];
#pragma unroll
        for (int e = 0; e < 8; ++e) s[e] = 0.0f;
#pragma unroll
        for (int d = 0; d < ED; ++d) {
            const float4 wv4 = *(const float4*)(WpT + ((size_t)(d * KK + k) * CC + o) * CC + ic);
            const ushort_t* wp = (const ushort_t*)&wv4;
#pragma unroll
            for (int e = 0; e < 8; ++e) s[e] += en[d] * bf2f(wp[e]);
        }
        ushort_t pack[8];
#pragma unroll
        for (int e = 0; e < 8; ++e) pack[e] = f2bf(s[e]);
        *(float4*)&Wt[o * XLD + k * 64 + ic] = *(float4*)pack;
    }
    __syncthreads();

    const int lane = tid & 63;
    const int l16 = lane & 15;
    const int quad = lane >> 4;
    const int bm = (tid >> 6) * 16;  // wave's 16 b-rows

    f32x4 acc[4];
#pragma unroll
    for (int ji = 0; ji < 4; ++ji) acc[ji] = (f32x4){0.f, 0.f, 0.f, 0.f};

#pragma unroll
    for (int kc = 0; kc < 6; ++kc) {  // K = 192 = 6 x 32
        const short8 av = *(const short8*)&xg[(bm + l16) * XLD + kc * 32 + quad * 8];
#pragma unroll
        for (int ji = 0; ji < 4; ++ji) {
            const short8 bv = *(const short8*)&Wt[(ji * 16 + l16) * XLD + kc * 32 + quad * 8];
            acc[ji] = __builtin_amdgcn_mfma_f32_16x16x32_bf16(av, bv, acc[ji], 0, 0, 0);
        }
    }

    // C/D: col o = l16 + 16*ji, row b = bm + quad*4 + r.
#pragma unroll
    for (int ji = 0; ji < 4; ++ji) {
        const int o = ji * 16 + l16;
        const float bo = bias_s[o];
#pragma unroll
        for (int r = 0; r < 4; ++r) {
            const int b = bm + quad * 4 + r;
            out[((size_t)b * NN + n) * CC + o] = acc[ji][r] + bo;
        }
    }
}
#undef XLD

// ---------------------------------------------------------------------------
// Host launch: 5 dispatches.
//   y2 = 2A(Ax) - x  ==  (2A^2 - I)x  =:  T2 @ x
//   -> [A; T2] @ x in ONE M=4096 GEMM (grid 256 = 1 block/CU, 8-phase).
// Workspace (bf16): Ab 8 | xT 16 | xN 16 | y1N 16 | y2N 16 (At aliases first
//   half — dead before gemm8 writes) | T2b 8 | WpT 0.24  = 84.1 MB.
// ---------------------------------------------------------------------------
extern "C" void kernel_launch(void* const* d_in, const int* in_sizes, int n_in,
                              void* d_out, int out_size, void* d_ws, size_t ws_size,
                              hipStream_t stream) {
    const float* x  = (const float*)d_in[0];
    const float* E  = (const float*)d_in[1];
    const float* Wp = (const float*)d_in[2];
    const float* bp = (const float*)d_in[3];

    ushort_t* Ab  = (ushort_t*)d_ws;                    // [2048][2048]
    ushort_t* xT  = Ab + (size_t)NN * NN;               // [4096][2048]
    ushort_t* xN  = xT + (size_t)JJ * NN;               // [2048][4096]
    ushort_t* y1N = xN + (size_t)NN * JJ;               // [2048][4096]
    ushort_t* y2N = y1N + (size_t)NN * JJ;              // [2048][4096]
    ushort_t* At  = y2N;                                // alias: [2048][2048], dead before y2N written
    ushort_t* T2b = y2N + (size_t)NN * JJ;              // [2048][2048]
    ushort_t* WpT = T2b + (size_t)NN * NN;              // [30][64][64]
    float* out = (float*)d_out;

    prep_kernel<<<2 * NN + ED * KK, 256, 0, stream>>>(E, x, Wp, Ab, xT, xN, WpT);
    trans_kernel<<<dim3(32, 32), 256, 0, stream>>>(Ab, At);
    // T2 = 2*A@A - I (row-major bf16)
    gemm_t2<<<dim3(16, 16), 256, 0, stream>>>(Ab, At, T2b);
    // [A; T2] @ x -> y1N, y2N (node-major), 256 blocks x 512 thr, 8-phase
    gemm8<<<256, 512, 0, stream>>>(Ab, T2b, xT, y1N, y2N);
    out_kernel<<<NN, 256, 0, stream>>>(E, WpT, bp, xN, y1N, y2N, out);
}

// Round 4
// 230.291 us; speedup vs baseline: 1.0075x; 1.0075x over previous
//
#include <hip/hip_runtime.h>

// B=64, N=2048, DIM_IN=DIM_OUT=64, CHEB_K=3, EMBED_DIM=10
#define NN 2048
#define BB 64
#define CC 64
#define ED 10
#define KK 3
#define JJ (BB * CC)   // 4096

typedef unsigned short ushort_t;
typedef __attribute__((ext_vector_type(8))) short short8;   // 8 bf16 = 4 VGPRs
typedef __attribute__((ext_vector_type(4))) float f32x4;

typedef const __attribute__((address_space(1))) unsigned* gptr_t;
typedef __attribute__((address_space(3))) unsigned* lptr_t;

static __device__ __forceinline__ ushort_t f2bf(float f) {
    union { float f; unsigned u; } x{f};
    unsigned r = x.u + 0x7FFF + ((x.u >> 16) & 1);  // RTN-even
    return (ushort_t)(r >> 16);
}
static __device__ __forceinline__ float bf2f(ushort_t h) {
    union { unsigned u; float f; } x;
    x.u = ((unsigned)h) << 16;
    return x.f;
}

// ---------------------------------------------------------------------------
// Kernel 1 (merged prep): blockIdx selects role.
//   [0, NN)            : supports — A_bf16[n][m] = softmax(relu(E E^T)) row n
//   [NN, 2*NN)         : transpose — x[b][n][c] -> xT[(b*64+c)][n], xN[n][j]
//   [2*NN, 2*NN+30)    : wprep — Wp[d][k][i][o] fp32 -> WpT[(d*3+k)][o][i] bf16
// ---------------------------------------------------------------------------
__global__ __launch_bounds__(256) void prep_kernel(const float* __restrict__ E,
                                                   const float* __restrict__ x,
                                                   const float* __restrict__ Wp,
                                                   ushort_t* __restrict__ Ab,
                                                   ushort_t* __restrict__ xT,
                                                   ushort_t* __restrict__ xN,
                                                   ushort_t* __restrict__ WpT) {
    const int bid = blockIdx.x;
    const int tid = threadIdx.x;

    __shared__ float tb[64][68];
    __shared__ float red[8];

    if (bid < NN) {
        // ---- supports row n = bid ----
        const int n = bid;
        float en[ED];
#pragma unroll
        for (int d = 0; d < ED; ++d) en[d] = E[n * ED + d];

        float sv[NN / 256];
        float lmax = 0.0f;  // relu >= 0
#pragma unroll
        for (int j = 0; j < NN / 256; ++j) {
            const int m = tid + j * 256;
            const float* Em = E + m * ED;
            float dot = 0.0f;
#pragma unroll
            for (int d = 0; d < ED; ++d) dot += en[d] * Em[d];
            float s = fmaxf(dot, 0.0f);
            sv[j] = s;
            lmax = fmaxf(lmax, s);
        }
#pragma unroll
        for (int off = 32; off > 0; off >>= 1) lmax = fmaxf(lmax, __shfl_down(lmax, off, 64));
        if ((tid & 63) == 0) red[tid >> 6] = lmax;
        __syncthreads();
        const float bmax = fmaxf(fmaxf(red[0], red[1]), fmaxf(red[2], red[3]));

        float lsum = 0.0f;
#pragma unroll
        for (int j = 0; j < NN / 256; ++j) {
            sv[j] = __expf(sv[j] - bmax);
            lsum += sv[j];
        }
#pragma unroll
        for (int off = 32; off > 0; off >>= 1) lsum += __shfl_down(lsum, off, 64);
        if ((tid & 63) == 0) red[4 + (tid >> 6)] = lsum;
        __syncthreads();
        const float inv = 1.0f / (red[4] + red[5] + red[6] + red[7]);

#pragma unroll
        for (int j = 0; j < NN / 256; ++j) {
            Ab[(size_t)n * NN + tid + j * 256] = f2bf(sv[j] * inv);
        }
    } else if (bid < 2 * NN) {
        // ---- transpose tile ----
        const int t = bid - NN;
        const int n0 = (t & 31) * 64;
        const int b = t >> 5;

#pragma unroll
        for (int l = 0; l < 4; ++l) {
            const int idx = tid + l * 256;
            const int nn = idx >> 4;
            const int c4 = (idx & 15) << 2;
            const float4 v = *(const float4*)(x + ((size_t)b * NN + n0 + nn) * CC + c4);
            tb[c4 + 0][nn] = v.x;
            tb[c4 + 1][nn] = v.y;
            tb[c4 + 2][nn] = v.z;
            tb[c4 + 3][nn] = v.w;
        }
        __syncthreads();

#pragma unroll
        for (int l = 0; l < 2; ++l) {
            const int idx = tid + l * 256;
            const int c = idx >> 3;
            const int ch = (idx & 7) << 3;
            ushort_t pack[8];
#pragma unroll
            for (int e = 0; e < 8; ++e) pack[e] = f2bf(tb[c][ch + e]);
            *(float4*)(xT + (size_t)(b * 64 + c) * NN + n0 + ch) = *(float4*)pack;
        }
#pragma unroll
        for (int l = 0; l < 2; ++l) {
            const int idx = tid + l * 256;
            const int nn = idx >> 3;
            const int cg = (idx & 7) << 3;
            ushort_t pack[8];
#pragma unroll
            for (int e = 0; e < 8; ++e) pack[e] = f2bf(tb[cg + e][nn]);
            *(float4*)(xN + (size_t)(n0 + nn) * JJ + b * 64 + cg) = *(float4*)pack;
        }
    } else {
        // ---- wprep slice dk = bid - 2*NN ----
        const int dk = bid - 2 * NN;
        const float* src = Wp + (size_t)dk * CC * CC;

#pragma unroll
        for (int l = 0; l < 4; ++l) {
            const int idx = tid + l * 256;
            const int i = idx >> 4;
            const int o4 = (idx & 15) << 2;
            const float4 v = *(const float4*)(src + i * CC + o4);
            tb[o4 + 0][i] = v.x;
            tb[o4 + 1][i] = v.y;
            tb[o4 + 2][i] = v.z;
            tb[o4 + 3][i] = v.w;
        }
        __syncthreads();

#pragma unroll
        for (int l = 0; l < 2; ++l) {
            const int idx = tid + l * 256;
            const int o = idx >> 3;
            const int ic = (idx & 7) << 3;
            ushort_t pack[8];
#pragma unroll
            for (int e = 0; e < 8; ++e) pack[e] = f2bf(tb[o][ic + e]);
            *(float4*)(WpT + (size_t)dk * CC * CC + o * CC + ic) = *(float4*)pack;
        }
    }
}

// ---------------------------------------------------------------------------
// Kernel 2: tiny bf16 transpose At[m][n] = Ab[n][m] (64x64 tiles, ~17 MB).
// ---------------------------------------------------------------------------
__global__ __launch_bounds__(256) void trans_kernel(const ushort_t* __restrict__ Ab,
                                                    ushort_t* __restrict__ At) {
    const int bx = blockIdx.x;  // source col-tile (At row-tile)
    const int by = blockIdx.y;  // source row-tile
    const int tid = threadIdx.x;
    __shared__ ushort_t tb[64][72];  // 144B stride: 16B-aligned rows

#pragma unroll
    for (int l = 0; l < 2; ++l) {
        const int idx = tid + l * 256;
        const int r = idx >> 3;
        const int c0 = (idx & 7) << 3;
        const float4 v = *(const float4*)(Ab + (size_t)(by * 64 + r) * NN + bx * 64 + c0);
        const ushort_t* p = (const ushort_t*)&v;
#pragma unroll
        for (int e = 0; e < 8; ++e) tb[c0 + e][r] = p[e];
    }
    __syncthreads();
#pragma unroll
    for (int l = 0; l < 2; ++l) {
        const int idx = tid + l * 256;
        const int m = idx >> 3;
        const int c0 = (idx & 7) << 3;
        ushort_t pack[8];
#pragma unroll
        for (int e = 0; e < 8; ++e) pack[e] = tb[m][c0 + e];
        *(float4*)(At + (size_t)(bx * 64 + m) * NN + by * 64 + c0) = *(float4*)pack;
    }
}

// ---------------------------------------------------------------------------
// Kernel 3: T2 = 2*A@A - I  (row-major bf16 out). Proven 128^2 dbuf structure,
// NT with Bt = A^T. 17.2 GF.
// ---------------------------------------------------------------------------
__global__ __launch_bounds__(256) void gemm_t2(const ushort_t* __restrict__ A,
                                               const ushort_t* __restrict__ Bt,
                                               ushort_t* __restrict__ C) {
    const int j0 = blockIdx.x * 128;
    const int m0 = blockIdx.y * 128;
    const int tid = threadIdx.x;
    const int lane = tid & 63;
    const int l16 = lane & 15;
    const int quad = lane >> 4;
    const int w = tid >> 6;
    const int wm = (w >> 1) * 64;
    const int wj = (w & 1) * 64;
    const int lr = lane >> 3;
    const int lc = lane & 7;
    const int swz = lc ^ lr;

    __shared__ ushort_t As[2][128 * 64];
    __shared__ ushort_t Bs[2][128 * 64];

    f32x4 acc[4][4];
#pragma unroll
    for (int mi = 0; mi < 4; ++mi)
#pragma unroll
        for (int ji = 0; ji < 4; ++ji) acc[mi][ji] = (f32x4){0.f, 0.f, 0.f, 0.f};

#pragma unroll
    for (int inst = 0; inst < 4; ++inst) {
        const int rbase = w * 32 + inst * 8;
        const int row = rbase + lr;
        __builtin_amdgcn_global_load_lds(
            (gptr_t)(A + (size_t)(m0 + row) * NN + swz * 8),
            (lptr_t)&As[0][rbase * 64], 16, 0, 0);
        __builtin_amdgcn_global_load_lds(
            (gptr_t)(Bt + (size_t)(j0 + row) * NN + swz * 8),
            (lptr_t)&Bs[0][rbase * 64], 16, 0, 0);
    }

    for (int it = 0; it < NN / 64; ++it) {
        const int cur = it & 1;
        __syncthreads();

        if (it + 1 < NN / 64) {
            const int k0 = (it + 1) * 64;
#pragma unroll
            for (int inst = 0; inst < 4; ++inst) {
                const int rbase = w * 32 + inst * 8;
                const int row = rbase + lr;
                __builtin_amdgcn_global_load_lds(
                    (gptr_t)(A + (size_t)(m0 + row) * NN + k0 + swz * 8),
                    (lptr_t)&As[1 - cur][rbase * 64], 16, 0, 0);
                __builtin_amdgcn_global_load_lds(
                    (gptr_t)(Bt + (size_t)(j0 + row) * NN + k0 + swz * 8),
                    (lptr_t)&Bs[1 - cur][rbase * 64], 16, 0, 0);
            }
        }

#pragma unroll
        for (int ks = 0; ks < 64; ks += 32) {
            const int qb = (ks >> 3) + quad;
            short8 av[4], bv[4];
#pragma unroll
            for (int mi = 0; mi < 4; ++mi) {
                const int rA = wm + mi * 16 + l16;
                av[mi] = *(const short8*)&As[cur][rA * 64 + ((qb ^ (rA & 7)) << 3)];
            }
#pragma unroll
            for (int ji = 0; ji < 4; ++ji) {
                const int rB = wj + ji * 16 + l16;
                bv[ji] = *(const short8*)&Bs[cur][rB * 64 + ((qb ^ (rB & 7)) << 3)];
            }
#pragma unroll
            for (int mi = 0; mi < 4; ++mi)
#pragma unroll
                for (int ji = 0; ji < 4; ++ji)
                    acc[mi][ji] = __builtin_amdgcn_mfma_f32_16x16x32_bf16(
                        av[mi], bv[ji], acc[mi][ji], 0, 0, 0);
        }
    }

    // C/D layout (16x16x32): col j = lane&15, row m = quad*4 + reg.
#pragma unroll
    for (int mi = 0; mi < 4; ++mi) {
#pragma unroll
        for (int ji = 0; ji < 4; ++ji) {
            const int j = j0 + wj + ji * 16 + l16;
            const int mb = m0 + wm + mi * 16 + quad * 4;
#pragma unroll
            for (int r = 0; r < 4; ++r) {
                const float v = 2.0f * acc[mi][ji][r] - ((mb + r) == j ? 1.0f : 0.0f);
                C[(size_t)(mb + r) * NN + j] = f2bf(v);
            }
        }
    }
}

// ---------------------------------------------------------------------------
// Kernel 4: 256^2 / BK=64 / 8-wave / counted-vmcnt GEMM with ROLLED pipeline.
// M=4096 ([A; T2]), N=4096, K=2048 -> grid 256 = 1 block/CU.
//
// Round-2 post-mortem: reads and MFMAs strictly alternated (reads in the
// barrier->lgkm window, matrix pipe idle) -> MfmaUtil 36%. This version rolls
// the schedule by one quadrant so EVERY ds_read batch issues right after an
// MFMA cluster (overlap at CU level):
//   - tail reads: B-q1 after MFMA(0,0); A-q1 after MFMA(0,1)
//   - the 4th quadrant MFMA(1,0) is deferred past the drain barrier, covering
//     the next tile's 12 top reads.
// Stage placement / vmcnt ledger / buffer fencing identical to the verified
// round-2 schedule:
//   R1: stage t_b h2 | R2: t_b h3 | R3: t_a+2 h2 | R4: t_a+2 h3,h0 vmcnt(6)
//   R5: t_a+2 h1    | R8: t_b+2 h0,h1 vmcnt(4)
// ---------------------------------------------------------------------------
#define STAGE_HALF(buf, h3, kt) do {                                                        \
    const ushort_t* s_ = ((h3) < 2) ? srcA : srcB;                                          \
    __builtin_amdgcn_global_load_lds(                                                       \
        (gptr_t)(s_ + (size_t)(((h3) & 1) * 2) * 64 * NN + (size_t)(kt) * 64),              \
        (lptr_t)&lds[buf][(h3) >= 2][(((h3) & 1) * 2) * 4096 + dstoff], 16, 0, 0);          \
    __builtin_amdgcn_global_load_lds(                                                       \
        (gptr_t)(s_ + (size_t)(((h3) & 1) * 2 + 1) * 64 * NN + (size_t)(kt) * 64),          \
        (lptr_t)&lds[buf][(h3) >= 2][(((h3) & 1) * 2 + 1) * 4096 + dstoff], 16, 0, 0);      \
} while (0)

#define LDA_Q(buf, qm) do {                                                                 \
    _Pragma("unroll") for (int mi_ = 0; mi_ < 4; ++mi_)                                     \
    _Pragma("unroll") for (int ks_ = 0; ks_ < 2; ++ks_)                                     \
        a[mi_][ks_] = *(const short8*)&lds[buf][0][((aRG + (qm) * 4 + mi_) * 2 + ks_) * 512 + rdofs]; \
} while (0)

#define LDB_Q(buf, qn) do {                                                                 \
    _Pragma("unroll") for (int ni_ = 0; ni_ < 2; ++ni_)                                     \
    _Pragma("unroll") for (int ks_ = 0; ks_ < 2; ++ks_)                                     \
        b[(qn) * 2 + ni_][ks_] = *(const short8*)&lds[buf][1][((bRG + (qn) * 2 + ni_) * 2 + ks_) * 512 + rdofs]; \
} while (0)

#define MFMA_Q(qm, qn) do {                                                                 \
    __builtin_amdgcn_s_setprio(1);                                                          \
    _Pragma("unroll") for (int mi_ = 0; mi_ < 4; ++mi_)                                     \
    _Pragma("unroll") for (int nn_ = 0; nn_ < 2; ++nn_) {                                   \
        acc[(qm) * 4 + mi_][(qn) * 2 + nn_] = __builtin_amdgcn_mfma_f32_16x16x32_bf16(      \
            a[mi_][0], b[(qn) * 2 + nn_][0], acc[(qm) * 4 + mi_][(qn) * 2 + nn_], 0, 0, 0); \
        acc[(qm) * 4 + mi_][(qn) * 2 + nn_] = __builtin_amdgcn_mfma_f32_16x16x32_bf16(      \
            a[mi_][1], b[(qn) * 2 + nn_][1], acc[(qm) * 4 + mi_][(qn) * 2 + nn_], 0, 0, 0); \
    }                                                                                       \
    __builtin_amdgcn_s_setprio(0);                                                          \
} while (0)

// barrier -> wait reads -> fence (rule 18) before MFMA
#define WAIT_READS do {                                                                     \
    __builtin_amdgcn_s_barrier();                                                           \
    asm volatile("s_waitcnt lgkmcnt(0)" ::: "memory");                                      \
    __builtin_amdgcn_sched_barrier(0);                                                      \
} while (0)

#define REGION_END do {                                                                     \
    __builtin_amdgcn_sched_barrier(0);                                                      \
    __builtin_amdgcn_s_barrier();                                                           \
} while (0)

__global__ __launch_bounds__(512, 2) void gemm8(const ushort_t* __restrict__ Ab,
                                                const ushort_t* __restrict__ T2b,
                                                const ushort_t* __restrict__ Bt,
                                                ushort_t* __restrict__ y1N,
                                                ushort_t* __restrict__ y2N) {
    // bijective XCD swizzle (gridDim.x = 256, 256 % 8 == 0)
    int bid = blockIdx.x;
    bid = (bid & 7) * 32 + (bid >> 3);
    const int bx = bid & 15;        // j-tile
    const int by = bid >> 4;        // m-tile (0..7 -> y1, 8..15 -> y2)
    const int j0 = bx * 256;
    const int m0 = by * 256;

    const ushort_t* Arows = (by < 8) ? (Ab + (size_t)m0 * NN) : (T2b + (size_t)(m0 - NN) * NN);
    const ushort_t* Brows = Bt + (size_t)j0 * NN;
    ushort_t* Crow = (by < 8) ? (y1N + (size_t)m0 * JJ) : (y2N + (size_t)(m0 - NN) * JJ);

    const int tid = threadIdx.x;
    const int w = tid >> 6;
    const int lane = tid & 63;
    const int l16 = lane & 15;
    const int quad = lane >> 4;
    const int wm = (w >> 2) * 128;  // wave output: rows [wm,wm+128) x cols [wn,wn+64)
    const int wn = (w & 3) * 64;
    const int aRG = (w >> 2) * 8;   // A 16-row subtile group base
    const int bRG = (w & 3) * 4;    // B 16-row subtile group base
    // swizzled ds_read offset (ushorts): row l16, k-chunk quad, st_16x32 XOR
    const int rdofs = l16 * 32 + ((quad * 8) ^ ((l16 & 8) * 2));

    // staging: linear LDS dest (base + lane*16B); inverse-swizzle the SOURCE
    const int r16s = lane >> 2;                       // dest row within subtile
    const int cx = (lane & 3) ^ ((r16s >> 3) << 1);   // inverse st_16x32 on k-chunk
    const int rowbase = (w >> 1) * 16 + r16s;         // row within 64-row group
    const int kofs = (w & 1) * 32 + cx * 8;           // k element offset in K-tile
    const ushort_t* srcA = Arows + (size_t)rowbase * NN + kofs;
    const ushort_t* srcB = Brows + (size_t)rowbase * NN + kofs;
    const int dstoff = tid * 8;                       // ushorts within 8KB unit

    __shared__ ushort_t lds[2][2][16384];  // [dbuf][A/B][32 KB tile] = 128 KB

    f32x4 acc[8][4];
#pragma unroll
    for (int mi = 0; mi < 8; ++mi)
#pragma unroll
        for (int ni = 0; ni < 4; ++ni) acc[mi][ni] = (f32x4){0.f, 0.f, 0.f, 0.f};

    short8 a[4][2], b[4][2];

    // Prologue: tile0 all 4 halves + tile1 h0,h1 (A); vmcnt(4) -> tile0 landed.
    STAGE_HALF(0, 0, 0); STAGE_HALF(0, 1, 0); STAGE_HALF(0, 2, 0); STAGE_HALF(0, 3, 0);
    STAGE_HALF(1, 0, 1); STAGE_HALF(1, 1, 1);
    asm volatile("s_waitcnt vmcnt(4)" ::: "memory");
    __builtin_amdgcn_s_barrier();

    // 16 iterations x 2 K-tiles (K = 2048 = 32 x BK64). buf0 = even tiles,
    // buf1 = odd tiles.
#pragma unroll 1
    for (int i = 0; i < 16; ++i) {
        const int tb_ = 2 * i + 1;
        const int ta2 = 2 * i + 2;
        const int tb2 = 2 * i + 3;
        const bool stg = (i < 15);

        // R1: pending MFMA(1,0) of tile 2i-1 (buf1 frags) covers top reads
        if (i) MFMA_Q(1, 0);
        LDA_Q(0, 0); LDB_Q(0, 0);
        STAGE_HALF(1, 2, tb_);
        WAIT_READS;
        MFMA_Q(0, 0);
        LDB_Q(0, 1);            // tail read: B-q1 (buf0), overlaps MFMA above
        REGION_END;
        // R2
        STAGE_HALF(1, 3, tb_);
        WAIT_READS;
        MFMA_Q(0, 1);
        LDA_Q(0, 1);            // tail read: A-q1 (buf0)
        REGION_END;
        // R3
        if (stg) STAGE_HALF(0, 2, ta2);
        WAIT_READS;
        MFMA_Q(1, 1);
        REGION_END;
        // R4: drain t_b (MFMA(1,0) deferred to R5, past the drain)
        if (stg) {
            STAGE_HALF(0, 3, ta2); STAGE_HALF(0, 0, ta2);
            asm volatile("s_waitcnt vmcnt(6)" ::: "memory");
        } else {
            asm volatile("s_waitcnt vmcnt(0)" ::: "memory");
        }
        __builtin_amdgcn_s_barrier();
        // R5: deferred MFMA(1,0) of tile 2i (buf0 frags) covers buf1 top reads
        MFMA_Q(1, 0);
        LDA_Q(1, 0); LDB_Q(1, 0);
        if (stg) STAGE_HALF(0, 1, ta2);
        WAIT_READS;
        MFMA_Q(0, 0);
        LDB_Q(1, 1);            // tail read: B-q1 (buf1)
        REGION_END;
        // R6 (no stage; single-barrier cadence)
        asm volatile("s_waitcnt lgkmcnt(0)" ::: "memory");
        __builtin_amdgcn_sched_barrier(0);
        MFMA_Q(0, 1);
        LDA_Q(1, 1);            // tail read: A-q1 (buf1)
        REGION_END;
        // R7 (no stage)
        asm volatile("s_waitcnt lgkmcnt(0)" ::: "memory");
        __builtin_amdgcn_sched_barrier(0);
        MFMA_Q(1, 1);
        REGION_END;
        // R8: drain t_a+2 (MFMA(1,0) deferred into next iter's R1)
        if (stg) {
            STAGE_HALF(1, 0, tb2); STAGE_HALF(1, 1, tb2);
            asm volatile("s_waitcnt vmcnt(4)" ::: "memory");
        }
        __builtin_amdgcn_s_barrier();
    }
    // Final deferred quadrant: tile 31 (buf1) MFMA(1,0)
    MFMA_Q(1, 0);

    // Epilogue: C/D col = l16, row = quad*4 + r. Row-major bf16 out.
#pragma unroll
    for (int mi = 0; mi < 8; ++mi) {
#pragma unroll
        for (int ni = 0; ni < 4; ++ni) {
            const int j = j0 + wn + ni * 16 + l16;
            const int mb = wm + mi * 16 + quad * 4;
#pragma unroll
            for (int r = 0; r < 4; ++r)
                Crow[(size_t)(mb + r) * JJ + j] = f2bf(acc[mi][ni][r]);
        }
    }
}

#undef STAGE_HALF
#undef LDA_Q
#undef LDB_Q
#undef MFMA_Q
#undef WAIT_READS
#undef REGION_END

// ---------------------------------------------------------------------------
// Kernel 5: MFMA epilogue (unchanged from the verified round-4 version).
// One block per node n: [B=64 x KI=192] @ [KI=192 x O=64] via 24 MFMAs/wave.
// ---------------------------------------------------------------------------
#define XLD 200  // LDS row stride (bf16): 400 B -> 2-way bank alias (free)
__global__ __launch_bounds__(256) void out_kernel(const float* __restrict__ E,
                                                  const ushort_t* __restrict__ WpT,
                                                  const float* __restrict__ bp,
                                                  const ushort_t* __restrict__ xN,
                                                  const ushort_t* __restrict__ y1N,
                                                  const ushort_t* __restrict__ y2N,
                                                  float* __restrict__ out) {
    const int n = blockIdx.x;
    const int tid = threadIdx.x;

    __shared__ ushort_t xg[BB * XLD];  // 25.6 KB: xg[b][k*64+i]
    __shared__ ushort_t Wt[CC * XLD];  // 25.6 KB: Wt[o][k*64+i]
    __shared__ float en_s[ED];
    __shared__ float bias_s[CC];

    if (tid < ED) en_s[tid] = E[n * ED + tid];
    __syncthreads();

    float en[ED];
#pragma unroll
    for (int d = 0; d < ED; ++d) en[d] = en_s[d];

    if (tid < CC) {
        float bsum = 0.0f;
#pragma unroll
        for (int d = 0; d < ED; ++d) bsum += en[d] * bp[d * CC + tid];
        bias_s[tid] = bsum;
    }

    // stage X rows: 3 sources x 512 chunks of 8 bf16 (contiguous 8 KB each)
#pragma unroll
    for (int k = 0; k < KK; ++k) {
        const ushort_t* src = (k == 0) ? xN : (k == 1) ? y1N : y2N;
        const float4* srow = (const float4*)(src + (size_t)n * JJ);
        for (int idx = tid; idx < JJ / 8; idx += 256) {
            *(float4*)&xg[(idx >> 3) * XLD + k * 64 + ((idx & 7) << 3)] = srow[idx];
        }
    }

    // synthesize Wt[o][ki] bf16: 1536 chunks of 8, fp32 accumulate over d
    for (int t = tid; t < CC * 24; t += 256) {
        const int o = t / 24;
        const int kc = t % 24;
        const int k = kc >> 3;
        const int ic = (kc & 7) << 3;
        float s[8];
#pragma unroll
        for (int e = 0; e < 8; ++e) s[e] = 0.0f;
#pragma unroll
        for (int d = 0; d < ED; ++d) {
            const float4 wv4 = *(const float4*)(WpT + ((size_t)(d * KK + k) * CC + o) * CC + ic);
            const ushort_t* wp = (const ushort_t*)&wv4;
#pragma unroll
            for (int e = 0; e < 8; ++e) s[e] += en[d] * bf2f(wp[e]);
        }
        ushort_t pack[8];
#pragma unroll
        for (int e = 0; e < 8; ++e) pack[e] = f2bf(s[e]);
        *(float4*)&Wt[o * XLD + k * 64 + ic] = *(float4*)pack;
    }
    __syncthreads();

    const int lane = tid & 63;
    const int l16 = lane & 15;
    const int quad = lane >> 4;
    const int bm = (tid >> 6) * 16;  // wave's 16 b-rows

    f32x4 acc[4];
#pragma unroll
    for (int ji = 0; ji < 4; ++ji) acc[ji] = (f32x4){0.f, 0.f, 0.f, 0.f};

#pragma unroll
    for (int kc = 0; kc < 6; ++kc) {  // K = 192 = 6 x 32
        const short8 av = *(const short8*)&xg[(bm + l16) * XLD + kc * 32 + quad * 8];
#pragma unroll
        for (int ji = 0; ji < 4; ++ji) {
            const short8 bv = *(const short8*)&Wt[(ji * 16 + l16) * XLD + kc * 32 + quad * 8];
            acc[ji] = __builtin_amdgcn_mfma_f32_16x16x32_bf16(av, bv, acc[ji], 0, 0, 0);
        }
    }

    // C/D: col o = l16 + 16*ji, row b = bm + quad*4 + r.
#pragma unroll
    for (int ji = 0; ji < 4; ++ji) {
        const int o = ji * 16 + l16;
        const float bo = bias_s[o];
#pragma unroll
        for (int r = 0; r < 4; ++r) {
            const int b = bm + quad * 4 + r;
            out[((size_t)b * NN + n) * CC + o] = acc[ji][r] + bo;
        }
    }
}
#undef XLD

// ---------------------------------------------------------------------------
// Host launch: 5 dispatches.
//   y2 = 2A(Ax) - x  ==  (2A^2 - I)x  =:  T2 @ x
//   -> [A; T2] @ x in ONE M=4096 GEMM (grid 256 = 1 block/CU).
// Workspace (bf16): Ab 8 | xT 16 | xN 16 | y1N 16 | y2N 16 (At aliases first
//   half — dead before gemm8 writes) | T2b 8 | WpT 0.24  = 84.1 MB.
// ---------------------------------------------------------------------------
extern "C" void kernel_launch(void* const* d_in, const int* in_sizes, int n_in,
                              void* d_out, int out_size, void* d_ws, size_t ws_size,
                              hipStream_t stream) {
    const float* x  = (const float*)d_in[0];
    const float* E  = (const float*)d_in[1];
    const float* Wp = (const float*)d_in[2];
    const float* bp = (const float*)d_in[3];

    ushort_t* Ab  = (ushort_t*)d_ws;                    // [2048][2048]
    ushort_t* xT  = Ab + (size_t)NN * NN;               // [4096][2048]
    ushort_t* xN  = xT + (size_t)JJ * NN;               // [2048][4096]
    ushort_t* y1N = xN + (size_t)NN * JJ;               // [2048][4096]
    ushort_t* y2N = y1N + (size_t)NN * JJ;              // [2048][4096]
    ushort_t* At  = y2N;                                // alias: [2048][2048], dead before y2N written
    ushort_t* T2b = y2N + (size_t)NN * JJ;              // [2048][2048]
    ushort_t* WpT = T2b + (size_t)NN * NN;              // [30][64][64]
    float* out = (float*)d_out;

    prep_kernel<<<2 * NN + ED * KK, 256, 0, stream>>>(E, x, Wp, Ab, xT, xN, WpT);
    trans_kernel<<<dim3(32, 32), 256, 0, stream>>>(Ab, At);
    // T2 = 2*A@A - I (row-major bf16)
    gemm_t2<<<dim3(16, 16), 256, 0, stream>>>(Ab, At, T2b);
    // [A; T2] @ x -> y1N, y2N (node-major), 256 blocks x 512 thr, rolled pipe
    gemm8<<<256, 512, 0, stream>>>(Ab, T2b, xT, y1N, y2N);
    out_kernel<<<NN, 256, 0, stream>>>(E, WpT, bp, xN, y1N, y2N, out);
}